// Round 3
// baseline (229.641 us; speedup 1.0000x reference)
//
#include <hip/hip_runtime.h>

// Derivative1D: y[b, i, c] = x[b, i+1, c] - x[b, i, c]
// x: (B=64, L=16384, C=32) fp32 contiguous; y: (B, L-1, C) fp32.
// Flattened per batch: out[r] = x[r + C] - x[r], r in [0, (L-1)*C).
// Pure streaming kernel. V2: 4 float4 per thread (MLP/ILP), nontemporal
// stores (output is write-once; keep L2/L3 for the input stream).
// V2b: use native clang ext_vector types (HIP float4 is a struct and
// __builtin_nontemporal_store rejects it).

typedef float f32x4 __attribute__((ext_vector_type(4)));

constexpr int B = 64;
constexpr int L = 16384;
constexpr int C = 32;
constexpr int PER_BATCH    = (L - 1) * C;      // 524256 floats per batch (out)
constexpr int PER_BATCH_V4 = PER_BATCH / 4;    // 131064 float4 per batch (exact)
constexpr int IN_PER_BATCH = L * C;            // 524288 floats per batch (in)

constexpr int BLOCK  = 256;
constexpr int UNROLL = 4;
constexpr int TILE   = BLOCK * UNROLL;         // 1024 float4 per block

__global__ __launch_bounds__(BLOCK) void deriv1d_kernel(const float* __restrict__ x,
                                                        float* __restrict__ out) {
    const int b    = blockIdx.y;
    const int base = blockIdx.x * TILE + threadIdx.x;

    const float* xb = x   + (size_t)b * IN_PER_BATCH;
    float*       ob = out + (size_t)b * PER_BATCH;

    f32x4 a[UNROLL], n[UNROLL];
    int   idx[UNROLL];
    bool  ok[UNROLL];

    // Issue all loads first: 4 independent load-pairs in flight per thread.
#pragma unroll
    for (int k = 0; k < UNROLL; ++k) {
        idx[k] = base + k * BLOCK;             // stays fully coalesced per wave
        ok[k]  = idx[k] < PER_BATCH_V4;
        if (ok[k]) {
            const float* p = xb + (size_t)idx[k] * 4;
            a[k] = *reinterpret_cast<const f32x4*>(p);
            n[k] = *reinterpret_cast<const f32x4*>(p + C);
        }
    }

#pragma unroll
    for (int k = 0; k < UNROLL; ++k) {
        if (ok[k]) {
            f32x4 d = n[k] - a[k];
            __builtin_nontemporal_store(d, reinterpret_cast<f32x4*>(ob + (size_t)idx[k] * 4));
        }
    }
}

extern "C" void kernel_launch(void* const* d_in, const int* in_sizes, int n_in,
                              void* d_out, int out_size, void* d_ws, size_t ws_size,
                              hipStream_t stream) {
    const float* x = (const float*)d_in[0];
    float* out = (float*)d_out;

    // 131064 float4 per batch, 1024 per block -> 128 blocks_x (tail masked)
    dim3 grid((PER_BATCH_V4 + TILE - 1) / TILE, B);
    dim3 block(BLOCK);
    deriv1d_kernel<<<grid, block, 0, stream>>>(x, out);
}

// Round 4
// 229.093 us; speedup vs baseline: 1.0024x; 1.0024x over previous
//
#include <hip/hip_runtime.h>

// Derivative1D: y[b, i, c] = x[b, i+1, c] - x[b, i, c]
// x: (B=64, L=16384, C=32) fp32 contiguous; y: (B, L-1, C) fp32.
// Flattened per batch: out[r] = x[r + C] - x[r], r in [0, (L-1)*C).
// Pure streaming kernel.
// V3: 4 float4 per thread (MLP/ILP), NORMAL stores.
//     (V2b's nontemporal stores regressed +7us: for a write-once stream,
//      L2 write-back buffering overlaps the HBM drain with later work;
//      nt forced the drain into the kernel's critical path.)

typedef float f32x4 __attribute__((ext_vector_type(4)));

constexpr int B = 64;
constexpr int L = 16384;
constexpr int C = 32;
constexpr int PER_BATCH    = (L - 1) * C;      // 524256 floats per batch (out)
constexpr int PER_BATCH_V4 = PER_BATCH / 4;    // 131064 float4 per batch (exact)
constexpr int IN_PER_BATCH = L * C;            // 524288 floats per batch (in)

constexpr int BLOCK  = 256;
constexpr int UNROLL = 4;
constexpr int TILE   = BLOCK * UNROLL;         // 1024 float4 per block

__global__ __launch_bounds__(BLOCK) void deriv1d_kernel(const float* __restrict__ x,
                                                        float* __restrict__ out) {
    const int b    = blockIdx.y;
    const int base = blockIdx.x * TILE + threadIdx.x;

    const float* xb = x   + (size_t)b * IN_PER_BATCH;
    float*       ob = out + (size_t)b * PER_BATCH;

    f32x4 a[UNROLL], n[UNROLL];
    int   idx[UNROLL];
    bool  ok[UNROLL];

    // Issue all loads first: 4 independent load-pairs in flight per thread.
#pragma unroll
    for (int k = 0; k < UNROLL; ++k) {
        idx[k] = base + k * BLOCK;             // stays fully coalesced per wave
        ok[k]  = idx[k] < PER_BATCH_V4;
        if (ok[k]) {
            const float* p = xb + (size_t)idx[k] * 4;
            a[k] = *reinterpret_cast<const f32x4*>(p);
            n[k] = *reinterpret_cast<const f32x4*>(p + C);
        }
    }

#pragma unroll
    for (int k = 0; k < UNROLL; ++k) {
        if (ok[k]) {
            f32x4 d = n[k] - a[k];
            *reinterpret_cast<f32x4*>(ob + (size_t)idx[k] * 4) = d;
        }
    }
}

extern "C" void kernel_launch(void* const* d_in, const int* in_sizes, int n_in,
                              void* d_out, int out_size, void* d_ws, size_t ws_size,
                              hipStream_t stream) {
    const float* x = (const float*)d_in[0];
    float* out = (float*)d_out;

    // 131064 float4 per batch, 1024 per block -> 128 blocks_x (tail masked)
    dim3 grid((PER_BATCH_V4 + TILE - 1) / TILE, B);
    dim3 block(BLOCK);
    deriv1d_kernel<<<grid, block, 0, stream>>>(x, out);
}